// Round 2
// baseline (49.437 us; speedup 1.0000x reference)
//
#include <hip/hip_runtime.h>
#include <hip/hip_bf16.h>
#include <math.h>

typedef __bf16 bf16;
typedef __bf16 bf16x8 __attribute__((ext_vector_type(8)));
typedef float  f32x4  __attribute__((ext_vector_type(4)));

static constexpr int kTokens = 32768;   // B*S = 8*4096
static constexpr int kH   = 768;
static constexpr int kC   = 64;
static constexpr int kNW  = 80;         // 64 e1 cols + 1 sc col + 15 zero pad
static constexpr int kKSplit = 4;       // one K-quarter per wave
static constexpr int kKPer   = kH / kKSplit;  // 192

// ---------- prep: build Wt[kNW][kH] bf16 = [W_e1^T | w_sc | 0...], and b_sc ----------
__global__ void prep_kernel(const float* __restrict__ W_ct,
                            const float* __restrict__ b_ct,
                            const float* __restrict__ W_cd,
                            const float* __restrict__ b_cd,
                            const float* __restrict__ W_e1,
                            bf16* __restrict__ Wt,
                            float* __restrict__ bsc) {
    int gidx = blockIdx.x * blockDim.x + threadIdx.x;
    const int total = kNW * kH;
    if (gidx < total) {
        int n = gidx / kH;
        int k = gidx - n * kH;
        float v = 0.f;
        if (n < kC) {
            v = W_e1[k * kC + n];                 // transpose of W_e1 (H,C)
        } else if (n == kC) {
            float s = 0.f;
            for (int c = 0; c < kC; ++c) s += W_ct[k * kC + c] * W_cd[c];
            v = s;                                // w_sc = W_ct @ W_cd
        }
        Wt[gidx] = (bf16)v;
    } else if (gidx == total) {
        float s = b_cd[0];
        for (int c = 0; c < kC; ++c) s += b_ct[c] * W_cd[c];
        bsc[0] = s;                               // b_sc = b_ct @ W_cd + b_cd
    }
}

// ---------- main: (32768 x 768) @ (768 x 80) bf16 MFMA, no LDS in main loop ----------
// Block = 4 waves, all on the SAME 16-token band, each owning one K-quarter.
// Grid = 2048 blocks -> 8 blocks/CU available; launch_bounds caps VGPR for 4/CU.
__global__ __launch_bounds__(256, 4) void incong_main(
    const float* __restrict__ hs,      // [kTokens][kH] f32
    const bf16*  __restrict__ Wt,      // [kNW][kH] bf16
    const float* __restrict__ bsc_p,
    const float* __restrict__ b_e1,
    const float* __restrict__ W_e2,
    const float* __restrict__ b_e2,
    float* __restrict__ out)           // [3][kTokens]
{
    __shared__ float red[3][64][21];   // +1 pad; only touched once at the end

    const int tid  = threadIdx.x;
    const int lane = tid & 63;
    const int wv   = tid >> 6;         // K-quarter 0..3
    const int tok0 = blockIdx.x * 16;
    const int r16  = lane & 15;
    const int kg   = lane >> 4;        // 0..3

    f32x4 acc[5];
    #pragma unroll
    for (int n = 0; n < 5; ++n) acc[n] = (f32x4){0.f, 0.f, 0.f, 0.f};

    const int k0 = wv * kKPer;
    const float* ap = hs + (size_t)(tok0 + r16) * kH + k0 + kg * 8;
    const bf16*  bp = Wt + (size_t)r16 * kH + k0 + kg * 8;

    #pragma unroll
    for (int ks = 0; ks < kKPer; ks += 32) {
        const float4 a0 = *reinterpret_cast<const float4*>(ap + ks);
        const float4 a1 = *reinterpret_cast<const float4*>(ap + ks + 4);
        bf16x8 af;
        af[0] = (bf16)a0.x; af[1] = (bf16)a0.y; af[2] = (bf16)a0.z; af[3] = (bf16)a0.w;
        af[4] = (bf16)a1.x; af[5] = (bf16)a1.y; af[6] = (bf16)a1.z; af[7] = (bf16)a1.w;
        #pragma unroll
        for (int n = 0; n < 5; ++n) {
            const bf16x8 bfr = *reinterpret_cast<const bf16x8*>(
                bp + (size_t)(n * 16) * kH + ks);
            acc[n] = __builtin_amdgcn_mfma_f32_16x16x32_bf16(af, bfr, acc[n], 0, 0, 0);
        }
    }

    // ---- cross-wave K reduction (one barrier total) ----
    if (wv) {
        #pragma unroll
        for (int n = 0; n < 5; ++n)
            #pragma unroll
            for (int r = 0; r < 4; ++r)
                red[wv - 1][lane][n * 4 + r] = acc[n][r];
    }
    __syncthreads();
    if (wv == 0) {
        #pragma unroll
        for (int w = 0; w < 3; ++w)
            #pragma unroll
            for (int n = 0; n < 5; ++n)
                #pragma unroll
                for (int r = 0; r < 4; ++r)
                    acc[n][r] += red[w][lane][n * 4 + r];

        // Epilogue. D layout (m89-verified): col = lane&15, row = kg*4 + reg.
        float part[4] = {0.f, 0.f, 0.f, 0.f};
        #pragma unroll
        for (int n = 0; n < 4; ++n) {
            const int cidx = n * 16 + r16;
            const float be = b_e1[cidx];
            const float we = W_e2[cidx];
            #pragma unroll
            for (int r = 0; r < 4; ++r)
                part[r] += fmaxf(acc[n][r] + be, 0.f) * we;
        }
        #pragma unroll
        for (int m = 1; m < 16; m <<= 1) {
            #pragma unroll
            for (int r = 0; r < 4; ++r) part[r] += __shfl_xor(part[r], m);
        }
        if (r16 == 0) {
            const float bsc = bsc_p[0];
            const float be2 = b_e2[0];
            #pragma unroll
            for (int r = 0; r < 4; ++r) {
                const int tok = tok0 + kg * 4 + r;
                const float sc = acc[4][r] + bsc;          // col 64 = w_sc column
                out[tok]               = 1.f / (1.f + __expf(-sc));
                out[kTokens + tok]     = 1.f / (1.f + __expf(-(part[r] + be2)));
                out[2 * kTokens + tok] = 1.f / 4096.f;     // mean of softmax == 1/S
            }
        }
    }
}

extern "C" void kernel_launch(void* const* d_in, const int* in_sizes, int n_in,
                              void* d_out, int out_size, void* d_ws, size_t ws_size,
                              hipStream_t stream) {
    const float* hs   = (const float*)d_in[0];
    // d_in[1] = attention_mask (all ones, unused by the reference math)
    const float* W_ct = (const float*)d_in[2];
    const float* b_ct = (const float*)d_in[3];
    const float* W_cd = (const float*)d_in[4];
    const float* b_cd = (const float*)d_in[5];
    const float* W_e1 = (const float*)d_in[6];
    const float* b_e1 = (const float*)d_in[7];
    const float* W_e2 = (const float*)d_in[8];
    const float* b_e2 = (const float*)d_in[9];
    // d_in[10..13] = W_q, b_q, W_k, b_k — unused (surprise is exactly 1/S)

    bf16*  Wt  = (bf16*)d_ws;
    float* bsc = (float*)((char*)d_ws + (size_t)kNW * kH * sizeof(bf16));

    const int prep_total = kNW * kH + 1;
    prep_kernel<<<(prep_total + 255) / 256, 256, 0, stream>>>(
        W_ct, b_ct, W_cd, b_cd, W_e1, Wt, bsc);

    incong_main<<<kTokens / 16, 256, 0, stream>>>(
        hs, Wt, bsc, b_e1, W_e2, b_e2, (float*)d_out);
}

// Round 3
// 30.454 us; speedup vs baseline: 1.6233x; 1.6233x over previous
//
#include <hip/hip_runtime.h>
#include <hip/hip_bf16.h>
#include <math.h>

typedef __bf16 bf16;
typedef __bf16 bf16x8 __attribute__((ext_vector_type(8)));
typedef float  f32x4  __attribute__((ext_vector_type(4)));

static constexpr int kTokens = 32768;   // B*S = 8*4096
static constexpr int kH   = 768;
static constexpr int kC   = 64;
static constexpr int kNW  = 80;         // 64 e1 cols + 1 sc col + 15 zero pad
static constexpr int kLDW = kH + 8;     // +8 bf16 pad: row stride 1552 B -> even bank spread

// ---------- prep: build Wt[kNW][kH] bf16 = [W_e1^T | w_sc | 0...], and b_sc ----------
__global__ void prep_kernel(const float* __restrict__ W_ct,
                            const float* __restrict__ b_ct,
                            const float* __restrict__ W_cd,
                            const float* __restrict__ b_cd,
                            const float* __restrict__ W_e1,
                            bf16* __restrict__ Wt,
                            float* __restrict__ bsc) {
    int gidx = blockIdx.x * blockDim.x + threadIdx.x;
    const int total = kNW * kH;
    if (gidx < total) {
        int n = gidx / kH;
        int k = gidx - n * kH;
        float v = 0.f;
        if (n < kC) {
            v = W_e1[k * kC + n];                 // transpose of W_e1 (H,C)
        } else if (n == kC) {
            float s = 0.f;
            for (int c = 0; c < kC; ++c) s += W_ct[k * kC + c] * W_cd[c];
            v = s;                                // w_sc = W_ct @ W_cd
        }
        Wt[gidx] = (bf16)v;
    } else if (gidx == total) {
        float s = b_cd[0];
        for (int c = 0; c < kC; ++c) s += b_ct[c] * W_cd[c];
        bsc[0] = s;                               // b_sc = b_ct @ W_cd + b_cd
    }
}

// ---------- main: (32768 x 768) @ (768 x 80) bf16 MFMA ----------
// B staged in LDS ONCE per block (124 KB, 1 block/CU). 8 waves/block, each wave
// owns one 16-token tile with FULL K: no K-split, no reduction, no loop barriers.
// Global traffic = A read exactly once (100.7 MB) + B once per block (30 MB).
__global__ __launch_bounds__(512, 2) void incong_main(
    const float* __restrict__ hs,      // [kTokens][kH] f32
    const bf16*  __restrict__ Wt,      // [kNW][kH] bf16
    const float* __restrict__ bsc_p,
    const float* __restrict__ b_e1,
    const float* __restrict__ W_e2,
    const float* __restrict__ b_e2,
    float* __restrict__ out)           // [3][kTokens]
{
    __shared__ bf16 lds_w[kNW][kLDW];

    const int tid  = threadIdx.x;
    const int lane = tid & 63;
    const int wv   = tid >> 6;         // 0..7: tile within block
    const int r16  = lane & 15;
    const int kg   = lane >> 4;        // 0..3

    // ---- stage full weight matrix into LDS (once) ----
    constexpr int kChunks = kNW * (kH / 8);   // 7680 bf16x8 chunks
    for (int c = tid; c < kChunks; c += 512) {
        int row = c / (kH / 8);
        int col = (c - row * (kH / 8)) * 8;
        *reinterpret_cast<bf16x8*>(&lds_w[row][col]) =
            *reinterpret_cast<const bf16x8*>(&Wt[(size_t)row * kH + col]);
    }
    __syncthreads();

    const int tok0 = (blockIdx.x * 8 + wv) * 16;

    f32x4 acc[5];
    #pragma unroll
    for (int n = 0; n < 5; ++n) acc[n] = (f32x4){0.f, 0.f, 0.f, 0.f};

    const float* ap = hs + (size_t)(tok0 + r16) * kH + kg * 8;
    const bf16* lp = &lds_w[r16][kg * 8];

    #pragma unroll 8
    for (int ks = 0; ks < kH; ks += 32) {
        const float4 a0 = *reinterpret_cast<const float4*>(ap + ks);
        const float4 a1 = *reinterpret_cast<const float4*>(ap + ks + 4);
        bf16x8 af;
        af[0] = (bf16)a0.x; af[1] = (bf16)a0.y; af[2] = (bf16)a0.z; af[3] = (bf16)a0.w;
        af[4] = (bf16)a1.x; af[5] = (bf16)a1.y; af[6] = (bf16)a1.z; af[7] = (bf16)a1.w;
        #pragma unroll
        for (int n = 0; n < 5; ++n) {
            const bf16x8 bfr = *reinterpret_cast<const bf16x8*>(
                lp + (size_t)(n * 16) * kLDW + ks);
            acc[n] = __builtin_amdgcn_mfma_f32_16x16x32_bf16(af, bfr, acc[n], 0, 0, 0);
        }
    }

    // ---- epilogue (per wave; D layout: col = lane&15, row = kg*4 + reg) ----
    float part[4] = {0.f, 0.f, 0.f, 0.f};
    #pragma unroll
    for (int n = 0; n < 4; ++n) {
        const int cidx = n * 16 + r16;
        const float be = b_e1[cidx];
        const float we = W_e2[cidx];
        #pragma unroll
        for (int r = 0; r < 4; ++r)
            part[r] += fmaxf(acc[n][r] + be, 0.f) * we;
    }
    #pragma unroll
    for (int m = 1; m < 16; m <<= 1) {
        #pragma unroll
        for (int r = 0; r < 4; ++r) part[r] += __shfl_xor(part[r], m);
    }
    if (r16 == 0) {
        const float bsc = bsc_p[0];
        const float be2 = b_e2[0];
        #pragma unroll
        for (int r = 0; r < 4; ++r) {
            const int tok = tok0 + kg * 4 + r;
            const float sc = acc[4][r] + bsc;          // col 64 = w_sc column
            out[tok]               = 1.f / (1.f + __expf(-sc));
            out[kTokens + tok]     = 1.f / (1.f + __expf(-(part[r] + be2)));
            out[2 * kTokens + tok] = 1.f / 4096.f;     // mean of softmax == 1/S
        }
    }
}

extern "C" void kernel_launch(void* const* d_in, const int* in_sizes, int n_in,
                              void* d_out, int out_size, void* d_ws, size_t ws_size,
                              hipStream_t stream) {
    const float* hs   = (const float*)d_in[0];
    // d_in[1] = attention_mask (all ones, unused by the reference math)
    const float* W_ct = (const float*)d_in[2];
    const float* b_ct = (const float*)d_in[3];
    const float* W_cd = (const float*)d_in[4];
    const float* b_cd = (const float*)d_in[5];
    const float* W_e1 = (const float*)d_in[6];
    const float* b_e1 = (const float*)d_in[7];
    const float* W_e2 = (const float*)d_in[8];
    const float* b_e2 = (const float*)d_in[9];
    // d_in[10..13] = W_q, b_q, W_k, b_k — unused (surprise is exactly 1/S)

    bf16*  Wt  = (bf16*)d_ws;
    float* bsc = (float*)((char*)d_ws + (size_t)kNW * kH * sizeof(bf16));

    const int prep_total = kNW * kH + 1;
    prep_kernel<<<(prep_total + 255) / 256, 256, 0, stream>>>(
        W_ct, b_ct, W_cd, b_cd, W_e1, Wt, bsc);

    incong_main<<<kTokens / (16 * 8), 512, 0, stream>>>(
        hs, Wt, bsc, b_e1, W_e2, b_e2, (float*)d_out);
}